// Round 3
// baseline (225.358 us; speedup 1.0000x reference)
//
#include <hip/hip_runtime.h>
#include <cstdint>
#include <cstddef>

#define EPS 1e-8f

// Fixed problem instance
#define Bsz 8
#define Nn  5
#define Kk  5
#define Qq  4
#define Ll  128
#define Ff  768
#define NQ  (Nn*Qq)            // 20
#define Tt  (2*Nn+1)           // 11
#define KL  (Kk*Ll)            // 640
#define ROWS_PER_B (NQ*Ll)     // 2560
#define NROWS (Bsz*ROWS_PER_B) // 20480
#define F4  (Ff/4)             // 192 float4 per row
#define BN  (Bsz*Nn)           // 40

#define S1_CHUNK 32
#define S1_CH    (KL / S1_CHUNK)   // 20 chunks -> 800 blocks

// ---------------- Stage 1: masked partial sums -> global atomic accum ----------------
// grid = BN * S1_CH = 800 blocks, 192 threads. Lane owns float4 column 4*tid;
// one full 768-float row per loop iteration (16 B/lane, fully coalesced).
__global__ __launch_bounds__(192) void stage1_partials(
    const float* __restrict__ sup,      // [B][N][K][L][F]
    const int*   __restrict__ Bm,       // [B][N][K][L]
    const int*   __restrict__ Im,
    float* __restrict__ accum,          // [BN][3][F]  (zeroed)
    float* __restrict__ cnt)            // [BN][2]     (zeroed)
{
    int blk  = blockIdx.x;
    int bn   = blk / S1_CH;
    int ch   = blk - bn * S1_CH;
    int pos0 = ch * S1_CHUNK;
    int tid  = threadIdx.x;

    const float4* sp = (const float4*)(sup + ((size_t)bn * KL + pos0) * Ff);
    const int*    bp = Bm + bn * KL + pos0;
    const int*    ip = Im + bn * KL + pos0;

    __shared__ float smB[S1_CHUNK];
    __shared__ float smI[S1_CHUNK];
    if (tid < S1_CHUNK) {
        smB[tid] = (float)bp[tid];
        smI[tid] = (float)ip[tid];
    }
    __syncthreads();

    float aBx=0,aBy=0,aBz=0,aBw=0, aIx=0,aIy=0,aIz=0,aIw=0, aOx=0,aOy=0,aOz=0,aOw=0;
    const float4* r = sp + tid;
    #pragma unroll 4
    for (int p = 0; p < S1_CHUNK; ++p, r += F4) {
        float mb = smB[p], mi = smI[p];
        float mo = 1.0f - mb - mi;
        float4 v = *r;
        aBx = fmaf(mb, v.x, aBx); aBy = fmaf(mb, v.y, aBy); aBz = fmaf(mb, v.z, aBz); aBw = fmaf(mb, v.w, aBw);
        aIx = fmaf(mi, v.x, aIx); aIy = fmaf(mi, v.y, aIy); aIz = fmaf(mi, v.z, aIz); aIw = fmaf(mi, v.w, aIw);
        aOx = fmaf(mo, v.x, aOx); aOy = fmaf(mo, v.y, aOy); aOz = fmaf(mo, v.z, aOz); aOw = fmaf(mo, v.w, aOw);
    }
    float* o = accum + (size_t)bn * (3 * Ff);
    int c = 4 * tid;
    atomicAdd(&o[c],   aBx); atomicAdd(&o[c+1],   aBy); atomicAdd(&o[c+2],   aBz); atomicAdd(&o[c+3],   aBw);
    atomicAdd(&o[Ff+c],aIx); atomicAdd(&o[Ff+c+1],aIy); atomicAdd(&o[Ff+c+2],aIz); atomicAdd(&o[Ff+c+3],aIw);
    atomicAdd(&o[2*Ff+c],aOx); atomicAdd(&o[2*Ff+c+1],aOy); atomicAdd(&o[2*Ff+c+2],aOz); atomicAdd(&o[2*Ff+c+3],aOw);

    if (tid == 0) { float s = 0; for (int p = 0; p < S1_CHUNK; ++p) s += smB[p]; atomicAdd(&cnt[bn*2],   s); }
    if (tid == 1) { float s = 0; for (int p = 0; p < S1_CHUNK; ++p) s += smI[p]; atomicAdd(&cnt[bn*2+1], s); }
}

// ---------------- Stage 3 (fused proto-normalize): logits + argmax + NLL ----------------
// grid = B * 160 blocks, 256 threads (4 waves); each wave handles 4 rows.
// Prototypes built in registers from raw sums (L2-resident), held as 33 float4/lane.
#define S3_BLOCKS_PER_B 160
#define S3_ROWS_PER_WAVE 4

__global__ __launch_bounds__(256) void stage3_logits(
    const float* __restrict__ query,    // [B][2560][F]
    const float* __restrict__ accum,    // [BN][3][F]
    const float* __restrict__ cnt,      // [BN][2]
    const int*   __restrict__ label,    // [B*2560]
    float* __restrict__ out_logits,     // [NROWS][T]
    float* __restrict__ out_pred,       // [NROWS]
    float* __restrict__ loss_out)       // [1]
{
    __shared__ float sLoss;

    int b  = blockIdx.x / S3_BLOCKS_PER_B;
    int rg = blockIdx.x - b * S3_BLOCKS_PER_B;
    int wave = threadIdx.x >> 6;
    int lane = threadIdx.x & 63;

    if (threadIdx.x == 0) sLoss = 0.0f;
    __syncthreads();

    // Build prototype registers from raw sums + counts.
    float4 P[Tt][3];
    float4 o0, o1, o2;
    o0.x=o0.y=o0.z=o0.w=0; o1=o0; o2=o0;
    float sumCB = 0.0f, sumCI = 0.0f;
    #pragma unroll
    for (int n = 0; n < Nn; ++n) {
        int bn = b * Nn + n;
        const float4* a = (const float4*)(accum + (size_t)bn * (3 * Ff));
        float cB = cnt[2*bn], cI = cnt[2*bn+1];
        float sB = 1.0f / (cB + EPS);
        float sI = 1.0f / (cI + EPS);
        float4 v;
        v = a[lane];            P[1+2*n][0].x=v.x*sB; P[1+2*n][0].y=v.y*sB; P[1+2*n][0].z=v.z*sB; P[1+2*n][0].w=v.w*sB;
        v = a[64+lane];         P[1+2*n][1].x=v.x*sB; P[1+2*n][1].y=v.y*sB; P[1+2*n][1].z=v.z*sB; P[1+2*n][1].w=v.w*sB;
        v = a[128+lane];        P[1+2*n][2].x=v.x*sB; P[1+2*n][2].y=v.y*sB; P[1+2*n][2].z=v.z*sB; P[1+2*n][2].w=v.w*sB;
        v = a[192+lane];        P[2+2*n][0].x=v.x*sI; P[2+2*n][0].y=v.y*sI; P[2+2*n][0].z=v.z*sI; P[2+2*n][0].w=v.w*sI;
        v = a[256+lane];        P[2+2*n][1].x=v.x*sI; P[2+2*n][1].y=v.y*sI; P[2+2*n][1].z=v.z*sI; P[2+2*n][1].w=v.w*sI;
        v = a[320+lane];        P[2+2*n][2].x=v.x*sI; P[2+2*n][2].y=v.y*sI; P[2+2*n][2].z=v.z*sI; P[2+2*n][2].w=v.w*sI;
        v = a[384+lane];        o0.x+=v.x; o0.y+=v.y; o0.z+=v.z; o0.w+=v.w;
        v = a[448+lane];        o1.x+=v.x; o1.y+=v.y; o1.z+=v.z; o1.w+=v.w;
        v = a[512+lane];        o2.x+=v.x; o2.y+=v.y; o2.z+=v.z; o2.w+=v.w;
        sumCB += cB; sumCI += cI;
    }
    float sO = 1.0f / ((float)(KL * Nn) - sumCB - sumCI + EPS);
    P[0][0].x=o0.x*sO; P[0][0].y=o0.y*sO; P[0][0].z=o0.z*sO; P[0][0].w=o0.w*sO;
    P[0][1].x=o1.x*sO; P[0][1].y=o1.y*sO; P[0][1].z=o1.z*sO; P[0][1].w=o1.w*sO;
    P[0][2].x=o2.x*sO; P[0][2].y=o2.y*sO; P[0][2].z=o2.z*sO; P[0][2].w=o2.w*sO;

    int row0 = rg * (4 * S3_ROWS_PER_WAVE) + wave * S3_ROWS_PER_WAVE;
    float wloss = 0.0f;

    for (int r = 0; r < S3_ROWS_PER_WAVE; ++r) {
        size_t grow = (size_t)b * ROWS_PER_B + row0 + r;
        const float4* q = (const float4*)(query + grow * Ff);
        float4 q0 = q[lane], q1 = q[64 + lane], q2 = q[128 + lane];
        int lab = label[grow];

        float acc[Tt];
        #pragma unroll
        for (int t = 0; t < Tt; ++t) {
            float d;
            d = q0.x * P[t][0].x;
            d = fmaf(q0.y, P[t][0].y, d); d = fmaf(q0.z, P[t][0].z, d); d = fmaf(q0.w, P[t][0].w, d);
            d = fmaf(q1.x, P[t][1].x, d); d = fmaf(q1.y, P[t][1].y, d);
            d = fmaf(q1.z, P[t][1].z, d); d = fmaf(q1.w, P[t][1].w, d);
            d = fmaf(q2.x, P[t][2].x, d); d = fmaf(q2.y, P[t][2].y, d);
            d = fmaf(q2.z, P[t][2].z, d); d = fmaf(q2.w, P[t][2].w, d);
            acc[t] = d;
        }
        // Butterfly-reduce all 11 accumulators together (independent chains -> ILP).
        #pragma unroll
        for (int off = 32; off > 0; off >>= 1) {
            #pragma unroll
            for (int t = 0; t < Tt; ++t) acc[t] += __shfl_xor(acc[t], off, 64);
        }
        // Every lane now holds the full 11-logit row.
        float m = acc[0]; int bt = 0;
        #pragma unroll
        for (int t = 1; t < Tt; ++t) if (acc[t] > m) { m = acc[t]; bt = t; }  // first-max
        float s = 0.0f;
        #pragma unroll
        for (int t = 0; t < Tt; ++t) s += __expf(acc[t] - m);
        float labv = acc[0];
        #pragma unroll
        for (int t = 1; t < Tt; ++t) labv = (lab == t) ? acc[t] : labv;
        float myv = acc[0];
        #pragma unroll
        for (int t = 1; t < Tt; ++t) myv = (lane == t) ? acc[t] : myv;

        if (lane < Tt) out_logits[grow * Tt + lane] = myv;
        if (lane == 0) out_pred[grow] = (float)bt;
        wloss += (m + __logf(s)) - labv;
    }

    if (lane == 0) atomicAdd(&sLoss, wloss);
    __syncthreads();
    if (threadIdx.x == 0) atomicAdd(loss_out, sLoss * (1.0f / (float)NROWS));
}

// ---------------- Host launch ----------------
extern "C" void kernel_launch(void* const* d_in, const int* in_sizes, int n_in,
                              void* d_out, int out_size, void* d_ws, size_t ws_size,
                              hipStream_t stream) {
    const float* sup   = (const float*)d_in[0];
    const float* query = (const float*)d_in[1];
    const int*   Bm    = (const int*)d_in[2];
    const int*   Im    = (const int*)d_in[3];
    const int*   lab   = (const int*)d_in[4];

    // ws layout: accum [BN][3][F] | cnt [BN][2]
    float* w     = (float*)d_ws;
    float* accum = w;                                   // 92160 floats
    float* cnt   = accum + (size_t)BN * 3 * Ff;         // 80 floats
    size_t zeroBytes = ((size_t)BN * 3 * Ff + 2 * BN) * sizeof(float);  // ~369 KB

    float* loss_out   = (float*)d_out;
    float* out_logits = (float*)d_out + 1;
    float* out_pred   = (float*)d_out + 1 + (size_t)NROWS * Tt;

    hipMemsetAsync(d_ws, 0, zeroBytes, stream);
    hipMemsetAsync(d_out, 0, sizeof(float), stream);

    stage1_partials<<<BN * S1_CH, 192, 0, stream>>>(sup, Bm, Im, accum, cnt);
    stage3_logits<<<Bsz * S3_BLOCKS_PER_B, 256, 0, stream>>>(query, accum, cnt, lab,
                                                             out_logits, out_pred, loss_out);
}